// Round 2
// baseline (96.890 us; speedup 1.0000x reference)
//
#include <hip/hip_runtime.h>

// EdgeCondGCNNTF: B=2,T=32,N=64,FIN=64,FOUT=64,EDIM=16.
// Factorized: agg = H_b @ Z[b,t],  Z[b,t,j,e,:] = xn[b,t,j,:] @ W2_e,
// plus rank-1 eb2 term via column-sum closed form, plus node_lin GEMM.
// Dual-dtype: device-side sniffer decides bf16 vs fp32 storage for in/out.

#define LSTR 72  // LDS f16 row stride: 144B -> 4-bank rotation, <=2-way conflicts (free, m136)
#define XSTR 68  // LDS f32 row stride for raw x: 272B -> 4-bank rotation

typedef unsigned short u16;
typedef _Float16 f16;
typedef _Float16 f16x8 __attribute__((ext_vector_type(8)));
typedef _Float16 f16x4 __attribute__((ext_vector_type(4)));
typedef float f32x4 __attribute__((ext_vector_type(4)));

__device__ __forceinline__ float bf2f(u16 u) {
    union { unsigned int i; float f; } c; c.i = ((unsigned int)u) << 16; return c.f;
}
__device__ __forceinline__ u16 f2bf(float f) {
    union { float f; unsigned int i; } c; c.f = f;
    unsigned int r = c.i + 0x7FFFu + ((c.i >> 16) & 1u);
    return (u16)(r >> 16);
}
__device__ __forceinline__ float gelu_exact(float v) {
    return 0.5f * v * (1.0f + erff(v * 0.70710678118654752440f));
}
__device__ __forceinline__ float loadf(const void* p, int i, bool bf) {
    return bf ? bf2f(((const u16*)p)[i]) : ((const float*)p)[i];
}
// Sniff x's storage dtype. Even-index u16s: bf16 data -> exponent ~127 (sane);
// fp32 data -> low mantissa halves -> uniform exponent (~20% sane). 256B read, safe both modes.
__device__ __forceinline__ int detect_bf16(const void* xp) {
    const u16* u = (const u16*)xp;
    int sane = 0;
    for (int k = 0; k < 64; ++k) {
        int e = (u[k * 2] >> 7) & 0xFF;
        sane += (e >= 100 && e <= 150);
    }
    return sane >= 40;
}

// ---- Kernel A: h = gelu(adj*ew1+eb1) -> H[b][e][i][j]; transpose ew2 -> W2t[e][o][f];
//      transpose nw -> NWt[o][f]. All f16 into workspace. 784*256 = 200704 items exactly.
__global__ __launch_bounds__(256) void precomp(
    const void* __restrict__ adj, const void* __restrict__ ew1, const void* __restrict__ eb1,
    const void* __restrict__ ew2, const void* __restrict__ nw, const void* __restrict__ x,
    f16* __restrict__ H, f16* __restrict__ W2t, f16* __restrict__ NWt)
{
    __shared__ int s_bf;
    if (threadIdx.x == 0) s_bf = detect_bf16(x);
    __syncthreads();
    const bool bf = (s_bf != 0);

    int idx = blockIdx.x * 256 + threadIdx.x;
    if (idx < 131072) {                       // B*EDIM*N*N
        int b = idx >> 16, rem = idx & 65535, e = rem >> 12, ij = rem & 4095;
        float a = loadf(adj, (b << 12) + ij, bf);
        float v = a * loadf(ew1, e, bf) + loadf(eb1, e, bf);
        H[idx] = (f16)gelu_exact(v);
    } else if (idx < 196608) {                // EDIM*FOUT*FIN
        int k = idx - 131072, e = k >> 12, of = k & 4095, o = of >> 6, f = of & 63;
        W2t[k] = (f16)loadf(ew2, (e << 12) + (f << 6) + o, bf);
    } else if (idx < 200704) {                // FOUT*FIN
        int k = idx - 196608, o = k >> 6, f = k & 63;
        NWt[k] = (f16)loadf(nw, (f << 6) + o, bf);
    }
}

// ---- Kernel B: one block per (b,t). Norm -> xn (LDS); loop e: Z_e = xn@W2_e (MFMA),
//      LDS-transpose, acc += H_be@Z_e (MFMA); + node_lin GEMM; + t2[o]+nb; GELU; store.
__global__ __launch_bounds__(256) void fused_main(
    const void* __restrict__ x, const void* __restrict__ eb2, const void* __restrict__ nb,
    const void* __restrict__ gw, const void* __restrict__ gb, const void* __restrict__ gms,
    const f16* __restrict__ H, const f16* __restrict__ W2t, const f16* __restrict__ NWt,
    void* __restrict__ out)
{
    __shared__ float xraw[64 * XSTR];
    __shared__ f16 xn_lds[64 * LSTR];
    __shared__ f16 w2t_lds[64 * LSTR];
    __shared__ f16 h_lds[64 * LSTR];
    __shared__ f16 zt_lds[64 * LSTR];
    __shared__ float red1[256];
    __shared__ float red2[256];
    __shared__ float af[64], cf[64], Sv[64], t2o[64];
    __shared__ int s_bf;

    const int tid  = threadIdx.x;
    const int bt   = blockIdx.x;        // 0..63 ; b = bt>>5
    const int b    = bt >> 5;
    const int lane = tid & 63;
    const int wave = tid >> 6;          // 4 waves; wave = output row-tile
    const int ln   = lane & 15;
    const int q    = lane >> 4;
    const int row  = tid >> 2;          // staging: 64 rows, 4 threads/row
    const int colb = (tid & 3) << 4;    // 0,16,32,48

    if (tid == 0) s_bf = detect_bf16(x);
    __syncthreads();
    const bool bf = (s_bf != 0);

    // stage raw x[b,t] into xraw (fp32), coalesced vector loads per mode
    {
        int base = (bt << 12) + (row << 6) + colb;
        if (bf) {
            const uint4* src = (const uint4*)((const u16*)x + base);
            uint4 v0 = src[0], v1 = src[1];
            const u16* p0 = (const u16*)&v0;
            const u16* p1 = (const u16*)&v1;
            #pragma unroll
            for (int k = 0; k < 8; ++k) {
                xraw[row * XSTR + colb + k]     = bf2f(p0[k]);
                xraw[row * XSTR + colb + 8 + k] = bf2f(p1[k]);
            }
        } else {
            const float4* src = (const float4*)((const float*)x + base);
            #pragma unroll
            for (int k = 0; k < 4; ++k) {
                float4 v = src[k];
                xraw[row * XSTR + colb + 4 * k]     = v.x;
                xraw[row * XSTR + colb + 4 * k + 1] = v.y;
                xraw[row * XSTR + colb + 4 * k + 2] = v.z;
                xraw[row * XSTR + colb + 4 * k + 3] = v.w;
            }
        }
    }
    __syncthreads();
    // per-feature mean / E[x^2] over the 64 nodes (column reduction, 4 partials)
    {
        int f = tid & 63, part = tid >> 6;
        float s1 = 0.f, s2 = 0.f;
        #pragma unroll
        for (int r = 0; r < 16; ++r) {
            float v = xraw[(part * 16 + r) * XSTR + f];
            s1 += v; s2 += v * v;
        }
        red1[part * 64 + f] = s1; red2[part * 64 + f] = s2;
    }
    __syncthreads();
    if (tid < 64) {
        float s1 = red1[tid] + red1[64 + tid] + red1[128 + tid] + red1[192 + tid];
        float s2 = red2[tid] + red2[64 + tid] + red2[128 + tid] + red2[192 + tid];
        float mean = s1 * 0.015625f;
        float var  = s2 * 0.015625f - mean * mean;   // ddof=0
        float inv  = rsqrtf(var + 1e-5f);
        float gwf = loadf(gw, tid, bf), gbf = loadf(gb, tid, bf), g = loadf(gms, 0, bf);
        float a = inv * gwf;
        af[tid] = a;
        cf[tid] = gbf - mean * g * a;
        // S[f] = sum_j xn[j,f] = 64*(mean*(1-gms)*inv*gw + gb)  (closed form)
        Sv[tid] = 64.f * (mean * (1.f - g) * a + gbf);
    }
    __syncthreads();
    // normalize: xraw -> xn_lds as f16
    {
        #pragma unroll
        for (int k = 0; k < 16; ++k) {
            int col = colb + k;
            xn_lds[row * LSTR + col] = (f16)(xraw[row * XSTR + col] * af[col] + cf[col]);
        }
    }
    // t2[o] = sum_f S[f]*eb2[f,o] partials (the eb2 part of edge_w)
    {
        int o = tid & 63, part = tid >> 6;
        float s = 0.f;
        #pragma unroll
        for (int r = 0; r < 16; ++r) {
            int f = part * 16 + r;
            s += Sv[f] * loadf(eb2, (f << 6) + o, bf);
        }
        red1[part * 64 + o] = s;
    }
    __syncthreads();
    if (tid < 64)
        t2o[tid] = red1[tid] + red1[64 + tid] + red1[128 + tid] + red1[192 + tid]
                 + loadf(nb, tid, bf);

    f32x4 acc[4];
    #pragma unroll
    for (int i2 = 0; i2 < 4; ++i2) acc[i2] = (f32x4){0.f, 0.f, 0.f, 0.f};

    for (int e = 0; e < 16; ++e) {
        __syncthreads();   // protect w2t/h/zt from previous iteration's readers
        {   // stage W2t_e (o x f) and H_be (i x j), 8KB each
            const uint4* s1 = (const uint4*)(W2t + (e << 12) + (row << 6) + colb);
            const uint4* s2 = (const uint4*)(H + ((b * 16 + e) << 12) + (row << 6) + colb);
            uint4 a0 = s1[0], a1 = s1[1], b0 = s2[0], b1 = s2[1];
            *(uint4*)&w2t_lds[row * LSTR + colb]     = a0;
            *(uint4*)&w2t_lds[row * LSTR + colb + 8] = a1;
            *(uint4*)&h_lds[row * LSTR + colb]       = b0;
            *(uint4*)&h_lds[row * LSTR + colb + 8]   = b1;
        }
        __syncthreads();
        // Z_e = xn @ W2_e : M=j (tile=wave), N=o, K=f=64. Write transposed zt[o][j] (f16).
        #pragma unroll
        for (int tn = 0; tn < 4; ++tn) {
            f32x4 z = {0.f, 0.f, 0.f, 0.f};
            #pragma unroll
            for (int kc = 0; kc < 2; ++kc) {
                f16x8 a  = *(const f16x8*)&xn_lds[(wave * 16 + ln) * LSTR + kc * 32 + q * 8];
                f16x8 bb = *(const f16x8*)&w2t_lds[(tn * 16 + ln) * LSTR + kc * 32 + q * 8];
                z = __builtin_amdgcn_mfma_f32_16x16x32_f16(a, bb, z, 0, 0, 0);
            }
            // C/D: row(j-in-tile)=q*4+reg, col(o-in-tile)=ln -> zt[o][j], 4 consecutive j
            f16x4 p;
            #pragma unroll
            for (int r = 0; r < 4; ++r) p[r] = (f16)z[r];
            *(f16x4*)&zt_lds[(tn * 16 + ln) * LSTR + wave * 16 + q * 4] = p;
        }
        __syncthreads();
        // acc += H_be @ Z_e : M=i (tile=wave), N=o, K=j=64
        #pragma unroll
        for (int tn = 0; tn < 4; ++tn) {
            #pragma unroll
            for (int kc = 0; kc < 2; ++kc) {
                f16x8 a  = *(const f16x8*)&h_lds[(wave * 16 + ln) * LSTR + kc * 32 + q * 8];
                f16x8 bb = *(const f16x8*)&zt_lds[(tn * 16 + ln) * LSTR + kc * 32 + q * 8];
                acc[tn] = __builtin_amdgcn_mfma_f32_16x16x32_f16(a, bb, acc[tn], 0, 0, 0);
            }
        }
    }
    __syncthreads();
    {   // stage NWt (o x f) for node_lin
        const uint4* s1 = (const uint4*)(NWt + (row << 6) + colb);
        uint4 a0 = s1[0], a1 = s1[1];
        *(uint4*)&w2t_lds[row * LSTR + colb]     = a0;
        *(uint4*)&w2t_lds[row * LSTR + colb + 8] = a1;
    }
    __syncthreads();
    // acc += xn @ nw
    #pragma unroll
    for (int tn = 0; tn < 4; ++tn) {
        #pragma unroll
        for (int kc = 0; kc < 2; ++kc) {
            f16x8 a  = *(const f16x8*)&xn_lds[(wave * 16 + ln) * LSTR + kc * 32 + q * 8];
            f16x8 bb = *(const f16x8*)&w2t_lds[(tn * 16 + ln) * LSTR + kc * 32 + q * 8];
            acc[tn] = __builtin_amdgcn_mfma_f32_16x16x32_f16(a, bb, acc[tn], 0, 0, 0);
        }
    }
    // epilogue: + t2[o] (nb folded in), exact GELU, store per mode
    {
        if (bf) {
            u16* ob = (u16*)out + (bt << 12);
            #pragma unroll
            for (int tn = 0; tn < 4; ++tn) {
                int o = tn * 16 + ln;
                float add = t2o[o];
                #pragma unroll
                for (int r = 0; r < 4; ++r) {
                    int i = wave * 16 + q * 4 + r;
                    ob[(i << 6) + o] = f2bf(gelu_exact(acc[tn][r] + add));
                }
            }
        } else {
            float* ob = (float*)out + (bt << 12);
            #pragma unroll
            for (int tn = 0; tn < 4; ++tn) {
                int o = tn * 16 + ln;
                float add = t2o[o];
                #pragma unroll
                for (int r = 0; r < 4; ++r) {
                    int i = wave * 16 + q * 4 + r;
                    ob[(i << 6) + o] = gelu_exact(acc[tn][r] + add);
                }
            }
        }
    }
}

extern "C" void kernel_launch(void* const* d_in, const int* in_sizes, int n_in,
                              void* d_out, int out_size, void* d_ws, size_t ws_size,
                              hipStream_t stream) {
    const void* x   = d_in[0];
    const void* adj = d_in[1];
    const void* ew1 = d_in[2];
    const void* eb1 = d_in[3];
    const void* ew2 = d_in[4];
    const void* eb2 = d_in[5];
    const void* nw  = d_in[6];
    const void* nb  = d_in[7];
    const void* gw  = d_in[8];
    const void* gb  = d_in[9];
    const void* gms = d_in[10];

    f16* H   = (f16*)d_ws;            // 131072 f16
    f16* W2t = H + 131072;            // 65536 f16
    f16* NWt = W2t + 65536;           // 4096 f16  (total 401408 B of ws)

    precomp<<<784, 256, 0, stream>>>(adj, ew1, eb1, ew2, nw, x, H, W2t, NWt);
    fused_main<<<64, 256, 0, stream>>>(x, eb2, nb, gw, gb, gms, H, W2t, NWt, d_out);
}

// Round 3
// 95.332 us; speedup vs baseline: 1.0163x; 1.0163x over previous
//
#include <hip/hip_runtime.h>

// EdgeCondGCNNTF: B=2,T=32,N=64,FIN=64,FOUT=64,EDIM=16.
// Factorized: agg = H_b @ Z[b,t],  Z[b,t,j,e,:] = xn[b,t,j,:] @ W2_e,
// rank-1 eb2 term via column-sum closed form, plus node_lin GEMM.
// v3: H/W2t/NWt MFMA fragments read DIRECTLY from global (L2-resident) ->
//     no staging barriers; e-loop chunked by 4 (8 barriers total); 128 blocks
//     (o-halves); xn frags hoisted; dual accumulation chains for ILP.

#define LSTR 72  // LDS f16 row stride: 144B (16B-aligned rows, conflicts spread across quarter-waves)
#define XSTR 68  // LDS f32 row stride for raw x
#define CE 4     // e-chunk depth

typedef unsigned short u16;
typedef _Float16 f16;
typedef _Float16 f16x8 __attribute__((ext_vector_type(8)));
typedef _Float16 f16x4 __attribute__((ext_vector_type(4)));
typedef float f32x4 __attribute__((ext_vector_type(4)));

__device__ __forceinline__ float bf2f(u16 u) {
    union { unsigned int i; float f; } c; c.i = ((unsigned int)u) << 16; return c.f;
}
__device__ __forceinline__ u16 f2bf(float f) {
    union { float f; unsigned int i; } c; c.f = f;
    unsigned int r = c.i + 0x7FFFu + ((c.i >> 16) & 1u);
    return (u16)(r >> 16);
}
__device__ __forceinline__ float gelu_exact(float v) {
    return 0.5f * v * (1.0f + erff(v * 0.70710678118654752440f));
}
__device__ __forceinline__ float loadf(const void* p, int i, bool bf) {
    return bf ? bf2f(((const u16*)p)[i]) : ((const float*)p)[i];
}
// Sniff x's storage dtype (bf16 vs fp32). Even-index u16s: bf16 -> sane exponents.
__device__ __forceinline__ int detect_bf16(const void* xp) {
    const u16* u = (const u16*)xp;
    int sane = 0;
    for (int k = 0; k < 64; ++k) {
        int e = (u[k * 2] >> 7) & 0xFF;
        sane += (e >= 100 && e <= 150);
    }
    return sane >= 40;
}

// ---- Kernel A: h = gelu(adj*ew1+eb1) -> H[b][e][i][j]; transpose ew2 -> W2t[e][o][f];
//      transpose nw -> NWt[o][f]. All f16 into workspace. 784*256 = 200704 items exactly.
__global__ __launch_bounds__(256) void precomp(
    const void* __restrict__ adj, const void* __restrict__ ew1, const void* __restrict__ eb1,
    const void* __restrict__ ew2, const void* __restrict__ nw, const void* __restrict__ x,
    f16* __restrict__ H, f16* __restrict__ W2t, f16* __restrict__ NWt)
{
    __shared__ int s_bf;
    if (threadIdx.x == 0) s_bf = detect_bf16(x);
    __syncthreads();
    const bool bf = (s_bf != 0);

    int idx = blockIdx.x * 256 + threadIdx.x;
    if (idx < 131072) {                       // B*EDIM*N*N
        int b = idx >> 16, rem = idx & 65535, e = rem >> 12, ij = rem & 4095;
        float a = loadf(adj, (b << 12) + ij, bf);
        float v = a * loadf(ew1, e, bf) + loadf(eb1, e, bf);
        H[idx] = (f16)gelu_exact(v);
    } else if (idx < 196608) {                // EDIM*FOUT*FIN
        int k = idx - 131072, e = k >> 12, of = k & 4095, o = of >> 6, f = of & 63;
        W2t[k] = (f16)loadf(ew2, (e << 12) + (f << 6) + o, bf);
    } else if (idx < 200704) {                // FOUT*FIN
        int k = idx - 196608, o = k >> 6, f = k & 63;
        NWt[k] = (f16)loadf(nw, (f << 6) + o, bf);
    }
}

// ---- Kernel B: 128 blocks = (b,t) x o-half. Norm in LDS; e-chunk loop:
//      Z = xn@W2 (B-frags from global), LDS transpose, acc += H@Z (A-frags from global).
__global__ __launch_bounds__(256) void fused_main(
    const void* __restrict__ x, const void* __restrict__ eb2, const void* __restrict__ nb,
    const void* __restrict__ gw, const void* __restrict__ gb, const void* __restrict__ gms,
    const f16* __restrict__ H, const f16* __restrict__ W2t, const f16* __restrict__ NWt,
    void* __restrict__ out)
{
    __shared__ float xraw[64 * XSTR];
    __shared__ f16 xn_lds[64 * LSTR];
    __shared__ f16 zt_lds[CE * 32 * LSTR];
    __shared__ float red1[256];
    __shared__ float red2[256];
    __shared__ float af[64], cf[64], Sv[64], t2o[64];
    __shared__ int s_bf;

    const int tid  = threadIdx.x;
    const int blk  = blockIdx.x;        // 0..127
    const int bt   = blk >> 1;          // 0..63
    const int half = blk & 1;           // o-half
    const int b    = bt >> 5;
    const int lane = tid & 63;
    const int wave = tid >> 6;          // 4 waves; wave = node row-tile
    const int ln   = lane & 15;
    const int q    = lane >> 4;
    const int row  = tid >> 2;          // staging: 64 rows, 4 threads/row
    const int colb = (tid & 3) << 4;    // 0,16,32,48

    if (tid == 0) s_bf = detect_bf16(x);
    __syncthreads();
    const bool bf = (s_bf != 0);

    // stage raw x[b,t] into xraw (fp32), coalesced vector loads per mode
    {
        int base = (bt << 12) + (row << 6) + colb;
        if (bf) {
            const uint4* src = (const uint4*)((const u16*)x + base);
            uint4 v0 = src[0], v1 = src[1];
            const u16* p0 = (const u16*)&v0;
            const u16* p1 = (const u16*)&v1;
            #pragma unroll
            for (int k = 0; k < 8; ++k) {
                xraw[row * XSTR + colb + k]     = bf2f(p0[k]);
                xraw[row * XSTR + colb + 8 + k] = bf2f(p1[k]);
            }
        } else {
            const float4* src = (const float4*)((const float*)x + base);
            #pragma unroll
            for (int k = 0; k < 4; ++k) {
                float4 v = src[k];
                xraw[row * XSTR + colb + 4 * k]     = v.x;
                xraw[row * XSTR + colb + 4 * k + 1] = v.y;
                xraw[row * XSTR + colb + 4 * k + 2] = v.z;
                xraw[row * XSTR + colb + 4 * k + 3] = v.w;
            }
        }
    }
    __syncthreads();
    // per-feature mean / E[x^2] over the 64 nodes (column reduction, 4 partials)
    {
        int f = tid & 63, part = tid >> 6;
        float s1 = 0.f, s2 = 0.f;
        #pragma unroll
        for (int r = 0; r < 16; ++r) {
            float v = xraw[(part * 16 + r) * XSTR + f];
            s1 += v; s2 += v * v;
        }
        red1[part * 64 + f] = s1; red2[part * 64 + f] = s2;
    }
    __syncthreads();
    if (tid < 64) {
        float s1 = red1[tid] + red1[64 + tid] + red1[128 + tid] + red1[192 + tid];
        float s2 = red2[tid] + red2[64 + tid] + red2[128 + tid] + red2[192 + tid];
        float mean = s1 * 0.015625f;
        float var  = s2 * 0.015625f - mean * mean;   // ddof=0
        float inv  = rsqrtf(var + 1e-5f);
        float gwf = loadf(gw, tid, bf), gbf = loadf(gb, tid, bf), g = loadf(gms, 0, bf);
        float a = inv * gwf;
        af[tid] = a;
        cf[tid] = gbf - mean * g * a;
        // S[f] = sum_j xn[j,f] = 64*(mean*(1-gms)*inv*gw + gb)  (closed form)
        Sv[tid] = 64.f * (mean * (1.f - g) * a + gbf);
    }
    __syncthreads();
    // normalize: xraw -> xn_lds as f16
    {
        #pragma unroll
        for (int k = 0; k < 16; ++k) {
            int col = colb + k;
            xn_lds[row * LSTR + col] = (f16)(xraw[row * XSTR + col] * af[col] + cf[col]);
        }
    }
    // t2[o] = sum_f S[f]*eb2[f,o] partials (the eb2 part of edge_w)
    {
        int o = tid & 63, part = tid >> 6;
        float s = 0.f;
        #pragma unroll
        for (int r = 0; r < 16; ++r) {
            int f = part * 16 + r;
            s += Sv[f] * loadf(eb2, (f << 6) + o, bf);
        }
        red1[part * 64 + o] = s;
    }
    __syncthreads();
    if (tid < 64)
        t2o[tid] = red1[tid] + red1[64 + tid] + red1[128 + tid] + red1[192 + tid]
                 + loadf(nb, tid, bf);
    __syncthreads();   // xn_lds complete for all waves

    // hoisted xn A-fragments (this wave's node row-tile, full K=f)
    f16x8 xa0 = *(const f16x8*)&xn_lds[(wave * 16 + ln) * LSTR + q * 8];
    f16x8 xa1 = *(const f16x8*)&xn_lds[(wave * 16 + ln) * LSTR + 32 + q * 8];

    // dual accumulation chains per o-tile (kc parity) for ILP
    f32x4 accA[2], accB[2];
    #pragma unroll
    for (int i2 = 0; i2 < 2; ++i2) {
        accA[i2] = (f32x4){0.f, 0.f, 0.f, 0.f};
        accB[i2] = (f32x4){0.f, 0.f, 0.f, 0.f};
    }

    for (int ec = 0; ec < 16 / CE; ++ec) {
        __syncthreads();   // zt reuse: prior readers done
        // phase 1: Z_e = xn @ W2_e for this chunk; B-frags direct from global W2t.
        #pragma unroll
        for (int el = 0; el < CE; ++el) {
            int e = ec * CE + el;
            const f16* w2b = W2t + (((e << 6) + (half << 5)) << 6);
            #pragma unroll
            for (int tn = 0; tn < 2; ++tn) {
                const f16* wrow = w2b + ((tn * 16 + ln) << 6);
                f16x8 b0 = *(const f16x8*)(wrow + q * 8);
                f16x8 b1 = *(const f16x8*)(wrow + 32 + q * 8);
                f32x4 z = {0.f, 0.f, 0.f, 0.f};
                z = __builtin_amdgcn_mfma_f32_16x16x32_f16(xa0, b0, z, 0, 0, 0);
                z = __builtin_amdgcn_mfma_f32_16x16x32_f16(xa1, b1, z, 0, 0, 0);
                // C/D: row(j)=q*4+r, col(o_local)=tn*16+ln -> zt[el][o_local][j]
                f16x4 p;
                #pragma unroll
                for (int r = 0; r < 4; ++r) p[r] = (f16)z[r];
                *(f16x4*)&zt_lds[(el * 32 + tn * 16 + ln) * LSTR + wave * 16 + q * 4] = p;
            }
        }
        __syncthreads();
        // phase 2: acc += H_be @ Z_e; A-frags direct from global H.
        #pragma unroll
        for (int el = 0; el < CE; ++el) {
            int e = ec * CE + el;
            const f16* hrow = H + (((b * 16 + e) << 12)) + ((wave * 16 + ln) << 6);
            f16x8 ha0 = *(const f16x8*)(hrow + q * 8);
            f16x8 ha1 = *(const f16x8*)(hrow + 32 + q * 8);
            #pragma unroll
            for (int tn = 0; tn < 2; ++tn) {
                f16x8 zb0 = *(const f16x8*)&zt_lds[(el * 32 + tn * 16 + ln) * LSTR + q * 8];
                f16x8 zb1 = *(const f16x8*)&zt_lds[(el * 32 + tn * 16 + ln) * LSTR + 32 + q * 8];
                accA[tn] = __builtin_amdgcn_mfma_f32_16x16x32_f16(ha0, zb0, accA[tn], 0, 0, 0);
                accB[tn] = __builtin_amdgcn_mfma_f32_16x16x32_f16(ha1, zb1, accB[tn], 0, 0, 0);
            }
        }
    }
    // node_lin: acc += xn @ nw (B-frags direct from global NWt)
    #pragma unroll
    for (int tn = 0; tn < 2; ++tn) {
        const f16* nrow = NWt + (((half * 32 + tn * 16 + ln)) << 6);
        f16x8 b0 = *(const f16x8*)(nrow + q * 8);
        f16x8 b1 = *(const f16x8*)(nrow + 32 + q * 8);
        accA[tn] = __builtin_amdgcn_mfma_f32_16x16x32_f16(xa0, b0, accA[tn], 0, 0, 0);
        accB[tn] = __builtin_amdgcn_mfma_f32_16x16x32_f16(xa1, b1, accB[tn], 0, 0, 0);
    }
    // epilogue: merge chains, + t2[o] (nb folded in), exact GELU, store per mode
    {
        if (bf) {
            u16* ob = (u16*)out + (bt << 12);
            #pragma unroll
            for (int tn = 0; tn < 2; ++tn) {
                int o = half * 32 + tn * 16 + ln;
                float add = t2o[o];
                #pragma unroll
                for (int r = 0; r < 4; ++r) {
                    int i = wave * 16 + q * 4 + r;
                    ob[(i << 6) + o] = f2bf(gelu_exact(accA[tn][r] + accB[tn][r] + add));
                }
            }
        } else {
            float* ob = (float*)out + (bt << 12);
            #pragma unroll
            for (int tn = 0; tn < 2; ++tn) {
                int o = half * 32 + tn * 16 + ln;
                float add = t2o[o];
                #pragma unroll
                for (int r = 0; r < 4; ++r) {
                    int i = wave * 16 + q * 4 + r;
                    ob[(i << 6) + o] = gelu_exact(accA[tn][r] + accB[tn][r] + add);
                }
            }
        }
    }
}

extern "C" void kernel_launch(void* const* d_in, const int* in_sizes, int n_in,
                              void* d_out, int out_size, void* d_ws, size_t ws_size,
                              hipStream_t stream) {
    const void* x   = d_in[0];
    const void* adj = d_in[1];
    const void* ew1 = d_in[2];
    const void* eb1 = d_in[3];
    const void* ew2 = d_in[4];
    const void* eb2 = d_in[5];
    const void* nw  = d_in[6];
    const void* nb  = d_in[7];
    const void* gw  = d_in[8];
    const void* gb  = d_in[9];
    const void* gms = d_in[10];

    f16* H   = (f16*)d_ws;            // 131072 f16
    f16* W2t = H + 131072;            // 65536 f16
    f16* NWt = W2t + 65536;           // 4096 f16  (total 401408 B of ws)

    precomp<<<784, 256, 0, stream>>>(adj, ew1, eb1, ew2, nw, x, H, W2t, NWt);
    fused_main<<<128, 256, 0, stream>>>(x, eb2, nb, gw, gb, gms, H, W2t, NWt, d_out);
}